// Round 7
// baseline (1793.217 us; speedup 1.0000x reference)
//
#include <hip/hip_runtime.h>

#define DIM 128
#define SLOTS 64

typedef __attribute__((ext_vector_type(8))) short bf16x8;
typedef __attribute__((ext_vector_type(4))) float f32x4;
typedef unsigned short u16;
typedef unsigned int u32;
typedef unsigned long long u64;

__device__ __forceinline__ float bf2f(u32 u) {
    return __builtin_bit_cast(float, u << 16);
}
__device__ __forceinline__ u16 f2bf(float f) {
    u32 u = __builtin_bit_cast(u32, f);
    u = (u + 0x7FFFu + ((u >> 16) & 1u)) >> 16;   // RNE
    return (u16)u;
}
__device__ __forceinline__ u32 pack2bf(float a, float b) {
    return (u32)f2bf(a) | ((u32)f2bf(b) << 16);
}

// ---------------- fused setup: deg atomics + bucket scatter + x->bf16 + Wt build x3 ----------------

__global__ __launch_bounds__(256) void k_setup(const int* __restrict__ row, const int* __restrict__ col,
                                               const int* __restrict__ et, const float* __restrict__ ew,
                                               int E, float* __restrict__ deg, int* __restrict__ fill,
                                               u64* __restrict__ ep,
                                               const float* __restrict__ x, u16* __restrict__ xb, int nx4,
                                               const float* __restrict__ W1, const float* __restrict__ W2,
                                               const float* __restrict__ W3,
                                               u16* __restrict__ Wt1, u16* __restrict__ Wt2,
                                               u16* __restrict__ Wt3, int nEb, int nXb) {
    int b = blockIdx.x, tid = threadIdx.x;
    if (b < nEb) {
        int e = b * 256 + tid;
        if (e < E) {
            int r = row[e], c = col[e];
            atomicAdd(&deg[c], 1.0f);                 // in-degree (col counts)
            int pos = atomicAdd(&fill[r], 1);         // bucket slot for row
            if (pos < SLOTS)
                ep[(size_t)r * SLOTS + pos] =
                    ((u64)__builtin_bit_cast(u32, ew[e]) << 32) | (u32)(c | (et[e] << 16));
        }
    } else if (b < nEb + nXb) {
        int i = (b - nEb) * 256 + tid;
        if (i < nx4) {
            float4 v = ((const float4*)x)[i];
            ushort4 o;
            o.x = f2bf(v.x); o.y = f2bf(v.y); o.z = f2bf(v.z); o.w = f2bf(v.w);
            ((ushort4*)xb)[i] = o;
        }
    } else {
        int b2 = b - nEb - nXb;                    // 0..767
        const float* W = b2 < 256 ? W1 : (b2 < 512 ? W2 : W3);
        u16* Wt = b2 < 256 ? Wt1 : (b2 < 512 ? Wt2 : Wt3);
        int o = (b2 & 255) * 256 + tid;            // 0..65535
        // fragment order with PERMUTED k: o = chunk*1024 + col*8 + s, k' = chunk*8 + s
        // float-col q = k'&127 maps to input dim i = 2*(q&63) + (q>>6); t = k'>>7
        int chunk = o >> 10;
        int c = (o >> 3) & 127;
        int kp = chunk * 8 + (o & 7);
        int q = kp & 127;
        int i = ((q & 63) << 1) | (q >> 6);
        int t = kp >> 7;
        Wt[o] = f2bf(W[t * 16384 + i * 128 + c]);
    }
}

__global__ void k_dis(const float* __restrict__ deg, float* __restrict__ dis, int N) {
    int i = blockIdx.x * blockDim.x + threadIdx.x;
    if (i < N) {
        float d = deg[i];
        dis[i] = d > 0.f ? rsqrtf(d) : 0.f;
    }
}

// ---------------- k_norm: fold full norm into bucket weights + zero-pad to multiple of 8 ----------------

__global__ __launch_bounds__(256) void k_norm(const int* __restrict__ fill,
                                              const float* __restrict__ dis,
                                              u64* __restrict__ ep, int N) {
    int wid = threadIdx.x >> 6, lane = threadIdx.x & 63;
    int n = blockIdx.x * 4 + wid;
    if (n >= N) return;
    int cnt = fill[n]; if (cnt > SLOTS) cnt = SLOTS;
    int padded = (cnt + 7) & ~7;
    float dn = dis[n];
    u64* eb = ep + (size_t)n * SLOTS;
    if (lane < cnt) {
        u64 q = eb[lane];
        u32 lo = (u32)q;
        float wgt = __builtin_bit_cast(float, (u32)(q >> 32)) * dn * dis[lo & 0xFFFF];
        eb[lane] = ((u64)__builtin_bit_cast(u32, wgt) << 32) | lo;
    } else if (lane < padded) {
        eb[lane] = 0;   // zero weight, col 0, type 0
    }
}

// ---------------- fused layer: POOLED gather (round table + ds_add_f32) -> MFMA ----------------
// block = 1024 thr / 16 waves / 16 nodes. Rounds (node, 8 slots) distributed round-robin
// over all 16 waves; accumulate into shared fp32 aggF via LDS atomics (uniform work, no stragglers).
// Dim d stored at float-col (d>>1) + (d&1)*64 -> lane stride 4B, 2-way bank alias (free).

template <int MODE>
__global__ __launch_bounds__(1024, 8) void k_layer(const u16* __restrict__ src,
                                                   const int* __restrict__ fill,
                                                   const u64* __restrict__ ep,
                                                   const u16* __restrict__ Wt,
                                                   const float* __restrict__ bias,
                                                   const float* __restrict__ x0,
                                                   const u16* __restrict__ z1b,
                                                   const u16* __restrict__ z2b,
                                                   float* __restrict__ outf,
                                                   u16* __restrict__ outb, int N) {
    __shared__ float aggF[16 * 512];   // 32 KB fp32 accumulators
    __shared__ u16 sB[16 * 512];       // 16 KB bf16 swizzled MFMA tile
    __shared__ u16 tab[128];           // round table: (node<<8) | slot_offset
    __shared__ int Ttot;
    int tid = threadIdx.x, wid = tid >> 6, lane = tid & 63;
    int n0 = blockIdx.x * 16;

    // zero accumulators
    ((f32x4*)aggF)[tid * 2]     = f32x4{0.f, 0.f, 0.f, 0.f};
    ((f32x4*)aggF)[tid * 2 + 1] = f32x4{0.f, 0.f, 0.f, 0.f};

    // wave 0: build round table from padded bucket counts
    if (wid == 0) {
        int R = 0;
        if (lane < 16) {
            int nn = n0 + lane;
            int c = (nn < N) ? fill[nn] : 0;
            if (c > SLOTS) c = SLOTS;
            R = ((c + 7) & ~7) >> 3;
        }
        int incl = R;
        #pragma unroll
        for (int off = 1; off < 16; off <<= 1) {
            int u = __shfl_up(incl, off);
            if (lane >= off) incl += u;
        }
        int excl = incl - R;
        for (int r = 0; r < R; r++)
            tab[excl + r] = (u16)((lane << 8) | (r * 8));
        if (lane == 15) Ttot = incl;
    }
    __syncthreads();

    // pooled gather
    const u16* xcol = src + (size_t)lane * 2;
    int T = Ttot;
    for (int t = wid; t < T; t += 16) {
        u32 entry = tab[t];
        int node = entry >> 8;
        int j0 = entry & 255;
        const u64* eb = ep + ((size_t)(n0 + node) * SLOTS + j0);
        u64 q0 = eb[0], q1 = eb[1], q2 = eb[2], q3 = eb[3];
        u64 q4 = eb[4], q5 = eb[5], q6 = eb[6], q7 = eb[7];
        u32 v0 = *(const u32*)(xcol + (size_t)((u32)q0 & 0xFFFF) * DIM);
        u32 v1 = *(const u32*)(xcol + (size_t)((u32)q1 & 0xFFFF) * DIM);
        u32 v2 = *(const u32*)(xcol + (size_t)((u32)q2 & 0xFFFF) * DIM);
        u32 v3 = *(const u32*)(xcol + (size_t)((u32)q3 & 0xFFFF) * DIM);
        u32 v4 = *(const u32*)(xcol + (size_t)((u32)q4 & 0xFFFF) * DIM);
        u32 v5 = *(const u32*)(xcol + (size_t)((u32)q5 & 0xFFFF) * DIM);
        u32 v6 = *(const u32*)(xcol + (size_t)((u32)q6 & 0xFFFF) * DIM);
        u32 v7 = *(const u32*)(xcol + (size_t)((u32)q7 & 0xFFFF) * DIM);
        float* arow = aggF + node * 512 + lane;
#define EDGE(q, v) { u32 lo_ = (u32)(q); float wg_ = __builtin_bit_cast(float, (u32)((q) >> 32)); \
        float* p_ = arow + ((lo_ >> 16) & 3) * 128; \
        atomicAdd(p_,      bf2f((v) & 0xFFFFu) * wg_); \
        atomicAdd(p_ + 64, bf2f((v) >> 16) * wg_); }
        EDGE(q0, v0); EDGE(q1, v1); EDGE(q2, v2); EDGE(q3, v3);
        EDGE(q4, v4); EDGE(q5, v5); EDGE(q6, v6); EDGE(q7, v7);
#undef EDGE
    }
    __syncthreads();

    // convert fp32 -> bf16 swizzled tile (thread -> row wid, 8 floats)
    {
        int r = wid;
        int c0 = lane * 8;
        const float* s = aggF + r * 512 + c0;
        u32 o0 = pack2bf(s[0], s[1]), o1 = pack2bf(s[2], s[3]);
        u32 o2 = pack2bf(s[4], s[5]), o3 = pack2bf(s[6], s[7]);
        u32 X = (u32)((r & 7) << 4);
        u32* d = (u32*)((char*)sB + r * 1024 + ((c0 * 2) ^ X));
        d[0] = o0; d[1] = o1; d[2] = o2; d[3] = o3;
    }
    __syncthreads();

    // MFMA: [16,512] @ [512,128]; waves 0..7 -> col tile wid*16
    if (wid < 8) {
        int lr = lane & 15, lk = lane >> 4;
        u32 X = (u32)((lr & 7) << 4);
        const char* ab = (const char*)sB + lr * 1024;
        const u16* bb = Wt + lk * 1024 + (wid * 16 + lr) * 8;
        f32x4 acc = {};
        #pragma unroll
        for (int ks = 0; ks < 16; ks++) {
            bf16x8 af = *(const bf16x8*)(ab + ((ks * 64 + lk * 16) ^ X));
            bf16x8 bfv = *(const bf16x8*)(bb + ks * 4096);
            acc = __builtin_amdgcn_mfma_f32_16x16x32_bf16(af, bfv, acc, 0, 0, 0);
        }

        // epilogue: col = lane&15 (+tile), row = (lane>>4)*4 + r
        int colg = wid * 16 + lr;
        float bv = bias[colg];
        #pragma unroll
        for (int r = 0; r < 4; r++) {
            int nn = n0 + lk * 4 + r;
            if (nn < N) {
                size_t idx = (size_t)nn * DIM + colg;
                float v = acc[r] + bv;
                v = v > 0.f ? v : 0.01f * v;
                if (MODE == 1)
                    outf[idx] = 0.25f * (x0[idx] + bf2f(z1b[idx]) + bf2f(z2b[idx]) + v);
                else
                    outb[idx] = f2bf(v);
            }
        }
    }
}

// ---------------- launch ----------------

extern "C" void kernel_launch(void* const* d_in, const int* in_sizes, int n_in,
                              void* d_out, int out_size, void* d_ws, size_t ws_size,
                              hipStream_t stream) {
    const float* x     = (const float*)d_in[0];
    const int*   eidx  = (const int*)d_in[1];
    const int*   etype = (const int*)d_in[2];
    const float* eattr = (const float*)d_in[3];
    const float* W1 = (const float*)d_in[4];
    const float* b1 = (const float*)d_in[5];
    const float* W2 = (const float*)d_in[6];
    const float* b2 = (const float*)d_in[7];
    const float* W3 = (const float*)d_in[8];
    const float* b3 = (const float*)d_in[9];

    const int E = in_sizes[2];
    const int N = in_sizes[0] / DIM;
    const int* row = eidx;
    const int* col = eidx + E;

    char* w = (char*)d_ws;
    size_t off = 0;
    auto alloc = [&](size_t bytes) { size_t o = off; off = (off + bytes + 255) & ~255ULL; return o; };
    size_t deg_off = alloc((size_t)N * 4);
    float* deg  = (float*)(w + deg_off);
    int*   fill = (int*)(w + alloc((size_t)N * 4));
    size_t zero_bytes = off - deg_off;
    float* dis  = (float*)(w + alloc((size_t)N * 4));
    u64*   ep   = (u64*)(w + alloc((size_t)N * SLOTS * 8));
    u16*   xb   = (u16*)(w + alloc((size_t)N * DIM * 2));
    u16*   z1b  = (u16*)(w + alloc((size_t)N * DIM * 2));
    u16*   z2b  = (u16*)(w + alloc((size_t)N * DIM * 2));
    u16*   Wt1  = (u16*)(w + alloc(65536 * 2));
    u16*   Wt2  = (u16*)(w + alloc(65536 * 2));
    u16*   Wt3  = (u16*)(w + alloc(65536 * 2));

    hipMemsetAsync(deg, 0, zero_bytes, stream);

    int nx4 = N * DIM / 4;
    int nEb = (E + 255) / 256;
    int nXb = (nx4 + 255) / 256;

    k_setup<<<nEb + nXb + 768, 256, 0, stream>>>(row, col, etype, eattr, E, deg, fill, ep,
                                                 x, xb, nx4, W1, W2, W3, Wt1, Wt2, Wt3, nEb, nXb);
    k_dis<<<(N + 255) / 256, 256, 0, stream>>>(deg, dis, N);
    k_norm<<<(N + 3) / 4, 256, 0, stream>>>(fill, dis, ep, N);

    int grid = (N + 15) / 16;
    k_layer<0><<<grid, 1024, 0, stream>>>(xb,  fill, ep, Wt1, b1, nullptr, nullptr, nullptr, nullptr, z1b, N);
    k_layer<0><<<grid, 1024, 0, stream>>>(z1b, fill, ep, Wt2, b2, nullptr, nullptr, nullptr, nullptr, z2b, N);
    k_layer<1><<<grid, 1024, 0, stream>>>(z2b, fill, ep, Wt3, b3, x, z1b, z2b, (float*)d_out, nullptr, N);
}

// Round 8
// 748.004 us; speedup vs baseline: 2.3973x; 2.3973x over previous
//
#include <hip/hip_runtime.h>

#define DIM 128
#define SLOTS 64

typedef __attribute__((ext_vector_type(8))) short bf16x8;
typedef __attribute__((ext_vector_type(4))) float f32x4;
typedef unsigned short u16;
typedef unsigned int u32;
typedef unsigned long long u64;

__device__ __forceinline__ float bf2f(u32 u) {
    return __builtin_bit_cast(float, u << 16);
}
__device__ __forceinline__ u16 f2bf(float f) {
    u32 u = __builtin_bit_cast(u32, f);
    u = (u + 0x7FFFu + ((u >> 16) & 1u)) >> 16;   // RNE
    return (u16)u;
}
__device__ __forceinline__ u32 pack2bf(float a, float b) {
    return (u32)f2bf(a) | ((u32)f2bf(b) << 16);
}

// ---------------- fused setup: deg/fill atomics (4 edges/thread) + bucket scatter + x->bf16 + Wt x3 ----------------

__global__ __launch_bounds__(256) void k_setup(const int* __restrict__ row, const int* __restrict__ col,
                                               const int* __restrict__ et, const float* __restrict__ ew,
                                               int E, int* __restrict__ deg, int* __restrict__ fill,
                                               u64* __restrict__ ep,
                                               const float* __restrict__ x, u16* __restrict__ xb, int nx4,
                                               const float* __restrict__ W1, const float* __restrict__ W2,
                                               const float* __restrict__ W3,
                                               u16* __restrict__ Wt1, u16* __restrict__ Wt2,
                                               u16* __restrict__ Wt3, int nEb, int nXb) {
    int b = blockIdx.x, tid = threadIdx.x;
    if (b < nEb) {
        int e0 = (b * 256 + tid) * 4;
        #pragma unroll
        for (int i = 0; i < 4; i++) {
            int e = e0 + i;
            if (e < E) {
                int r = row[e], c = col[e];
                atomicAdd(&deg[c], 1);                    // in-degree (col counts)
                int pos = atomicAdd(&fill[r], 1);         // bucket slot for row
                if (pos < SLOTS)
                    ep[(size_t)r * SLOTS + pos] =
                        ((u64)__builtin_bit_cast(u32, ew[e]) << 32) | (u32)(c | (et[e] << 16));
            }
        }
    } else if (b < nEb + nXb) {
        int i = (b - nEb) * 256 + tid;
        if (i < nx4) {
            float4 v = ((const float4*)x)[i];
            ushort4 o;
            o.x = f2bf(v.x); o.y = f2bf(v.y); o.z = f2bf(v.z); o.w = f2bf(v.w);
            ((ushort4*)xb)[i] = o;
        }
    } else {
        int b2 = b - nEb - nXb;                    // 0..767
        const float* W = b2 < 256 ? W1 : (b2 < 512 ? W2 : W3);
        u16* Wt = b2 < 256 ? Wt1 : (b2 < 512 ? Wt2 : Wt3);
        int o = (b2 & 255) * 256 + tid;            // 0..65535
        // fragment order with PERMUTED k: o = chunk*1024 + col*8 + s, k' = chunk*8 + s
        // float-col q = k'&127 maps to input dim i = 2*(q&63) + (q>>6); t = k'>>7
        int chunk = o >> 10;
        int c = (o >> 3) & 127;
        int kp = chunk * 8 + (o & 7);
        int q = kp & 127;
        int i = ((q & 63) << 1) | (q >> 6);
        int t = kp >> 7;
        Wt[o] = f2bf(W[t * 16384 + i * 128 + c]);
    }
}

// ---------------- k_norm: fold full norm (rsqrt inline) into bucket weights + zero-pad to x8 ----------------

__global__ __launch_bounds__(256) void k_norm(const int* __restrict__ fill,
                                              const int* __restrict__ deg,
                                              u64* __restrict__ ep, int N) {
    int wid = threadIdx.x >> 6, lane = threadIdx.x & 63;
    int n = blockIdx.x * 4 + wid;
    if (n >= N) return;
    int cnt = fill[n]; if (cnt > SLOTS) cnt = SLOTS;
    int padded = (cnt + 7) & ~7;
    int dgn = deg[n];
    float dn = dgn > 0 ? rsqrtf((float)dgn) : 0.f;
    u64* eb = ep + (size_t)n * SLOTS;
    if (lane < cnt) {
        u64 q = eb[lane];
        u32 lo = (u32)q;
        int dgc = deg[lo & 0xFFFF];
        float dc = dgc > 0 ? rsqrtf((float)dgc) : 0.f;
        float wgt = __builtin_bit_cast(float, (u32)(q >> 32)) * dn * dc;
        eb[lane] = ((u64)__builtin_bit_cast(u32, wgt) << 32) | lo;
    } else if (lane < padded) {
        eb[lane] = 0;   // zero weight, col 0, type 0
    }
}

// ---------------- fused layer: pooled gather (contiguous chunks, register accum, flush on switch) ----------------
// block = 1024 thr / 16 waves / 16 nodes. Round table built by wave 0; wave w takes rounds
// [w*L, (w+1)*L) -> each node's rounds contiguous -> register accumulation, ds_add only on flush.

template <int MODE>
__global__ __launch_bounds__(1024, 4) void k_layer(const u16* __restrict__ src,
                                                   const int* __restrict__ fill,
                                                   const u64* __restrict__ ep,
                                                   const u16* __restrict__ Wt,
                                                   const float* __restrict__ bias,
                                                   const float* __restrict__ x0,
                                                   const u16* __restrict__ z1b,
                                                   const u16* __restrict__ z2b,
                                                   float* __restrict__ outf,
                                                   u16* __restrict__ outb, int N) {
    __shared__ float aggF[16 * 512];   // 32 KB fp32 accumulators
    __shared__ u16 sB[16 * 512];       // 16 KB bf16 swizzled MFMA tile
    __shared__ u16 tab[128];           // round table: (node<<8) | slot_offset
    __shared__ int Ttot;
    int tid = threadIdx.x, wid = tid >> 6, lane = tid & 63;
    int n0 = blockIdx.x * 16;

    // zero accumulators
    ((f32x4*)aggF)[tid * 2]     = f32x4{0.f, 0.f, 0.f, 0.f};
    ((f32x4*)aggF)[tid * 2 + 1] = f32x4{0.f, 0.f, 0.f, 0.f};

    // wave 0: build round table from padded bucket counts
    if (wid == 0) {
        int R = 0;
        if (lane < 16) {
            int nn = n0 + lane;
            int c = (nn < N) ? fill[nn] : 0;
            if (c > SLOTS) c = SLOTS;
            R = ((c + 7) & ~7) >> 3;
        }
        int incl = R;
        #pragma unroll
        for (int off = 1; off < 16; off <<= 1) {
            int u = __shfl_up(incl, off);
            if (lane >= off) incl += u;
        }
        int excl = incl - R;
        for (int r = 0; r < R; r++)
            tab[excl + r] = (u16)((lane << 8) | (r * 8));
        if (lane == 15) Ttot = incl;
    }
    __syncthreads();

    // pooled gather: contiguous chunk per wave
    const u16* xcol = src + (size_t)lane * 2;
    int T = Ttot;
    int L = (T + 15) >> 4;
    int t0 = wid * L;
    int t1 = t0 + L; if (t1 > T) t1 = T;

    float2 a0 = {0.f, 0.f}, a1 = {0.f, 0.f}, a2 = {0.f, 0.f}, a3 = {0.f, 0.f};
    int cur = -1;

#define FLUSH() if (cur >= 0) { \
        float* arow_ = aggF + cur * 512 + lane; \
        atomicAdd(arow_ +   0, a0.x); atomicAdd(arow_ +  64, a0.y); \
        atomicAdd(arow_ + 128, a1.x); atomicAdd(arow_ + 192, a1.y); \
        atomicAdd(arow_ + 256, a2.x); atomicAdd(arow_ + 320, a2.y); \
        atomicAdd(arow_ + 384, a3.x); atomicAdd(arow_ + 448, a3.y); }

    for (int t = t0; t < t1; t++) {
        u32 entry = tab[t];
        int node = entry >> 8;
        int j0 = entry & 255;
        if (node != cur) {
            FLUSH();
            cur = node;
            a0 = {0.f, 0.f}; a1 = {0.f, 0.f}; a2 = {0.f, 0.f}; a3 = {0.f, 0.f};
        }
        const u64* eb = ep + ((size_t)(n0 + node) * SLOTS + j0);
        u64 q0 = eb[0], q1 = eb[1], q2 = eb[2], q3 = eb[3];
        u64 q4 = eb[4], q5 = eb[5], q6 = eb[6], q7 = eb[7];
        u32 v0 = *(const u32*)(xcol + (size_t)((u32)q0 & 0xFFFF) * DIM);
        u32 v1 = *(const u32*)(xcol + (size_t)((u32)q1 & 0xFFFF) * DIM);
        u32 v2 = *(const u32*)(xcol + (size_t)((u32)q2 & 0xFFFF) * DIM);
        u32 v3 = *(const u32*)(xcol + (size_t)((u32)q3 & 0xFFFF) * DIM);
        u32 v4 = *(const u32*)(xcol + (size_t)((u32)q4 & 0xFFFF) * DIM);
        u32 v5 = *(const u32*)(xcol + (size_t)((u32)q5 & 0xFFFF) * DIM);
        u32 v6 = *(const u32*)(xcol + (size_t)((u32)q6 & 0xFFFF) * DIM);
        u32 v7 = *(const u32*)(xcol + (size_t)((u32)q7 & 0xFFFF) * DIM);
#define ACC(q, v) { float wgt_ = __builtin_bit_cast(float, (u32)((q) >> 32)); \
        float v0_ = bf2f((v) & 0xFFFFu) * wgt_, v1_ = bf2f((v) >> 16) * wgt_; \
        int t_ = (int)(((q) >> 16) & 3); \
        if (t_ == 0)      { a0.x += v0_; a0.y += v1_; } \
        else if (t_ == 1) { a1.x += v0_; a1.y += v1_; } \
        else if (t_ == 2) { a2.x += v0_; a2.y += v1_; } \
        else              { a3.x += v0_; a3.y += v1_; } }
        ACC(q0, v0); ACC(q1, v1); ACC(q2, v2); ACC(q3, v3);
        ACC(q4, v4); ACC(q5, v5); ACC(q6, v6); ACC(q7, v7);
#undef ACC
    }
    FLUSH();
#undef FLUSH
    __syncthreads();

    // convert fp32 -> bf16 swizzled tile (thread -> row wid, 8 floats at lane*8)
    {
        int r = wid;
        int c0 = lane * 8;
        const float* s = aggF + r * 512 + c0;
        u32 o0 = pack2bf(s[0], s[1]), o1 = pack2bf(s[2], s[3]);
        u32 o2 = pack2bf(s[4], s[5]), o3 = pack2bf(s[6], s[7]);
        u32 X = (u32)((r & 7) << 4);
        u32* d = (u32*)((char*)sB + r * 1024 + ((c0 * 2) ^ X));
        d[0] = o0; d[1] = o1; d[2] = o2; d[3] = o3;
    }
    __syncthreads();

    // MFMA: [16,512] @ [512,128]; waves 0..7 -> col tile wid*16
    if (wid < 8) {
        int lr = lane & 15, lk = lane >> 4;
        u32 X = (u32)((lr & 7) << 4);
        const char* ab = (const char*)sB + lr * 1024;
        const u16* bb = Wt + lk * 1024 + (wid * 16 + lr) * 8;
        f32x4 acc = {};
        #pragma unroll
        for (int ks = 0; ks < 16; ks++) {
            bf16x8 af = *(const bf16x8*)(ab + ((ks * 64 + lk * 16) ^ X));
            bf16x8 bfv = *(const bf16x8*)(bb + ks * 4096);
            acc = __builtin_amdgcn_mfma_f32_16x16x32_bf16(af, bfv, acc, 0, 0, 0);
        }

        // epilogue: col = lane&15 (+tile), row = (lane>>4)*4 + r
        int colg = wid * 16 + lr;
        float bv = bias[colg];
        #pragma unroll
        for (int r = 0; r < 4; r++) {
            int nn = n0 + lk * 4 + r;
            if (nn < N) {
                size_t idx = (size_t)nn * DIM + colg;
                float v = acc[r] + bv;
                v = v > 0.f ? v : 0.01f * v;
                if (MODE == 1)
                    outf[idx] = 0.25f * (x0[idx] + bf2f(z1b[idx]) + bf2f(z2b[idx]) + v);
                else
                    outb[idx] = f2bf(v);
            }
        }
    }
}

// ---------------- launch ----------------

extern "C" void kernel_launch(void* const* d_in, const int* in_sizes, int n_in,
                              void* d_out, int out_size, void* d_ws, size_t ws_size,
                              hipStream_t stream) {
    const float* x     = (const float*)d_in[0];
    const int*   eidx  = (const int*)d_in[1];
    const int*   etype = (const int*)d_in[2];
    const float* eattr = (const float*)d_in[3];
    const float* W1 = (const float*)d_in[4];
    const float* b1 = (const float*)d_in[5];
    const float* W2 = (const float*)d_in[6];
    const float* b2 = (const float*)d_in[7];
    const float* W3 = (const float*)d_in[8];
    const float* b3 = (const float*)d_in[9];

    const int E = in_sizes[2];
    const int N = in_sizes[0] / DIM;
    const int* row = eidx;
    const int* col = eidx + E;

    char* w = (char*)d_ws;
    size_t off = 0;
    auto alloc = [&](size_t bytes) { size_t o = off; off = (off + bytes + 255) & ~255ULL; return o; };
    size_t deg_off = alloc((size_t)N * 4);
    int*   deg  = (int*)(w + deg_off);
    int*   fill = (int*)(w + alloc((size_t)N * 4));
    size_t zero_bytes = off - deg_off;
    u64*   ep   = (u64*)(w + alloc((size_t)N * SLOTS * 8));
    u16*   xb   = (u16*)(w + alloc((size_t)N * DIM * 2));
    u16*   z1b  = (u16*)(w + alloc((size_t)N * DIM * 2));
    u16*   z2b  = (u16*)(w + alloc((size_t)N * DIM * 2));
    u16*   Wt1  = (u16*)(w + alloc(65536 * 2));
    u16*   Wt2  = (u16*)(w + alloc(65536 * 2));
    u16*   Wt3  = (u16*)(w + alloc(65536 * 2));

    hipMemsetAsync(deg, 0, zero_bytes, stream);

    int nx4 = N * DIM / 4;
    int nEb = (E + 1023) / 1024;    // 4 edges per thread
    int nXb = (nx4 + 255) / 256;

    k_setup<<<nEb + nXb + 768, 256, 0, stream>>>(row, col, etype, eattr, E, deg, fill, ep,
                                                 x, xb, nx4, W1, W2, W3, Wt1, Wt2, Wt3, nEb, nXb);
    k_norm<<<(N + 3) / 4, 256, 0, stream>>>(fill, deg, ep, N);

    int grid = (N + 15) / 16;
    k_layer<0><<<grid, 1024, 0, stream>>>(xb,  fill, ep, Wt1, b1, nullptr, nullptr, nullptr, nullptr, z1b, N);
    k_layer<0><<<grid, 1024, 0, stream>>>(z1b, fill, ep, Wt2, b2, nullptr, nullptr, nullptr, nullptr, z2b, N);
    k_layer<1><<<grid, 1024, 0, stream>>>(z2b, fill, ep, Wt3, b3, x, z1b, z2b, (float*)d_out, nullptr, N);
}

// Round 9
// 244.433 us; speedup vs baseline: 7.3362x; 3.0602x over previous
//
#include <hip/hip_runtime.h>

#define DIM 128
#define SLOTS 64

typedef __attribute__((ext_vector_type(8))) short bf16x8;
typedef __attribute__((ext_vector_type(4))) float f32x4;
typedef unsigned short u16;
typedef unsigned int u32;
typedef unsigned long long u64;

__device__ __forceinline__ float bf2f(u32 u) {
    return __builtin_bit_cast(float, u << 16);
}
__device__ __forceinline__ u16 f2bf(float f) {
    u32 u = __builtin_bit_cast(u32, f);
    u = (u + 0x7FFFu + ((u >> 16) & 1u)) >> 16;   // RNE
    return (u16)u;
}
__device__ __forceinline__ u32 pack2bf(float a, float b) {
    return (u32)f2bf(a) | ((u32)f2bf(b) << 16);
}

// ---------------- fused setup: deg/fill atomics (4 edges/thread) + bucket scatter + x->bf16 + Wt x3 ----------------

__global__ __launch_bounds__(256) void k_setup(const int* __restrict__ row, const int* __restrict__ col,
                                               const int* __restrict__ et, const float* __restrict__ ew,
                                               int E, int* __restrict__ deg, int* __restrict__ fill,
                                               u64* __restrict__ ep,
                                               const float* __restrict__ x, u16* __restrict__ xb, int nx4,
                                               const float* __restrict__ W1, const float* __restrict__ W2,
                                               const float* __restrict__ W3,
                                               u16* __restrict__ Wt1, u16* __restrict__ Wt2,
                                               u16* __restrict__ Wt3, int nEb, int nXb) {
    int b = blockIdx.x, tid = threadIdx.x;
    if (b < nEb) {
        int e0 = (b * 256 + tid) * 4;
        #pragma unroll
        for (int i = 0; i < 4; i++) {
            int e = e0 + i;
            if (e < E) {
                int r = row[e], c = col[e];
                atomicAdd(&deg[c], 1);                    // in-degree (col counts)
                int pos = atomicAdd(&fill[r], 1);         // bucket slot for row
                if (pos < SLOTS)
                    ep[(size_t)r * SLOTS + pos] =
                        ((u64)__builtin_bit_cast(u32, ew[e]) << 32) | (u32)(c | (et[e] << 16));
            }
        }
    } else if (b < nEb + nXb) {
        int i = (b - nEb) * 256 + tid;
        if (i < nx4) {
            float4 v = ((const float4*)x)[i];
            ushort4 o;
            o.x = f2bf(v.x); o.y = f2bf(v.y); o.z = f2bf(v.z); o.w = f2bf(v.w);
            ((ushort4*)xb)[i] = o;
        }
    } else {
        int b2 = b - nEb - nXb;                    // 0..767
        const float* W = b2 < 256 ? W1 : (b2 < 512 ? W2 : W3);
        u16* Wt = b2 < 256 ? Wt1 : (b2 < 512 ? Wt2 : Wt3);
        int o = (b2 & 255) * 256 + tid;            // 0..65535
        // natural fragment order: o = chunk*1024 + col*8 + s, k = chunk*8 + s = t*128 + i
        int chunk = o >> 10;
        int c = (o >> 3) & 127;
        int k = chunk * 8 + (o & 7);
        Wt[o] = f2bf(W[(k >> 7) * 16384 + (k & 127) * 128 + c]);
    }
}

// ---------------- k_norm: fold full norm (rsqrt inline) into bucket weights + zero-pad to x8 ----------------

__global__ __launch_bounds__(256) void k_norm(const int* __restrict__ fill,
                                              const int* __restrict__ deg,
                                              u64* __restrict__ ep, int N) {
    int wid = threadIdx.x >> 6, lane = threadIdx.x & 63;
    int n = blockIdx.x * 4 + wid;
    if (n >= N) return;
    int cnt = fill[n]; if (cnt > SLOTS) cnt = SLOTS;
    int padded = (cnt + 7) & ~7;
    int dgn = deg[n];
    float dn = dgn > 0 ? rsqrtf((float)dgn) : 0.f;
    u64* eb = ep + (size_t)n * SLOTS;
    if (lane < cnt) {
        u64 q = eb[lane];
        u32 lo = (u32)q;
        int dgc = deg[lo & 0xFFFF];
        float dc = dgc > 0 ? rsqrtf((float)dgc) : 0.f;
        float wgt = __builtin_bit_cast(float, (u32)(q >> 32)) * dn * dc;
        eb[lane] = ((u64)__builtin_bit_cast(u32, wgt) << 32) | lo;
    } else if (lane < padded) {
        eb[lane] = 0;   // zero weight, col 0, type 0
    }
}

// ---------------- fused layer: bucket gather-aggregate -> LDS -> MFMA -> epilogue ----------------
// block = 1024 thr / 16 waves = 16 nodes, one node per wave; unmasked 8-wide gather rounds.
// __launch_bounds__(1024, 2): 2 blocks/CU (CUDA min-blocks semantics) -> 64-VGPR cap,
// enough for the 8-deep load pipeline (R5/R7/R8 showed (1024,>=4) strangles it to 32 VGPRs).

template <int MODE>
__global__ __launch_bounds__(1024, 2) void k_layer(const u16* __restrict__ src,
                                                   const int* __restrict__ fill,
                                                   const u64* __restrict__ ep,
                                                   const u16* __restrict__ Wt,
                                                   const float* __restrict__ bias,
                                                   const float* __restrict__ x0,
                                                   const u16* __restrict__ z1b,
                                                   const u16* __restrict__ z2b,
                                                   float* __restrict__ outf,
                                                   u16* __restrict__ outb, int N) {
    __shared__ u16 sA[16 * 512];   // 16 KB
    int tid = threadIdx.x, wid = tid >> 6, lane = tid & 63;
    int n0 = blockIdx.x * 16;
    int n = n0 + wid;

    float2 a0 = {0.f, 0.f}, a1 = {0.f, 0.f}, a2 = {0.f, 0.f}, a3 = {0.f, 0.f};
    int cnt = 0;
    if (n < N) {
        cnt = fill[n];
        if (cnt > SLOTS) cnt = SLOTS;
    }
    const u64* eb = ep + (size_t)n * SLOTS;
    const u16* xcol = src + (size_t)lane * 2;

#define ACC(q, v) { float wgt_ = __builtin_bit_cast(float, (u32)((q) >> 32)); \
        float v0_ = bf2f((v) & 0xFFFFu) * wgt_, v1_ = bf2f((v) >> 16) * wgt_; \
        int t_ = (int)(((q) >> 16) & 3); \
        if (t_ == 0)      { a0.x += v0_; a0.y += v1_; } \
        else if (t_ == 1) { a1.x += v0_; a1.y += v1_; } \
        else if (t_ == 2) { a2.x += v0_; a2.y += v1_; } \
        else              { a3.x += v0_; a3.y += v1_; } }

    // buckets are zero-padded to a multiple of 8 -> no masking
    for (int j = 0; j < cnt; j += 8) {
        u64 q0 = eb[j],     q1 = eb[j + 1], q2 = eb[j + 2], q3 = eb[j + 3];
        u64 q4 = eb[j + 4], q5 = eb[j + 5], q6 = eb[j + 6], q7 = eb[j + 7];
        u32 v0 = *(const u32*)(xcol + (size_t)((u32)q0 & 0xFFFF) * DIM);
        u32 v1 = *(const u32*)(xcol + (size_t)((u32)q1 & 0xFFFF) * DIM);
        u32 v2 = *(const u32*)(xcol + (size_t)((u32)q2 & 0xFFFF) * DIM);
        u32 v3 = *(const u32*)(xcol + (size_t)((u32)q3 & 0xFFFF) * DIM);
        u32 v4 = *(const u32*)(xcol + (size_t)((u32)q4 & 0xFFFF) * DIM);
        u32 v5 = *(const u32*)(xcol + (size_t)((u32)q5 & 0xFFFF) * DIM);
        u32 v6 = *(const u32*)(xcol + (size_t)((u32)q6 & 0xFFFF) * DIM);
        u32 v7 = *(const u32*)(xcol + (size_t)((u32)q7 & 0xFFFF) * DIM);
        ACC(q0, v0); ACC(q1, v1); ACC(q2, v2); ACC(q3, v3);
        ACC(q4, v4); ACC(q5, v5); ACC(q6, v6); ACC(q7, v7);
    }
#undef ACC

    // LDS store: row = wid (node), k = t*128 + 2*lane; swizzle byte ^= (row&7)<<4
    {
        u32 X = (u32)((wid & 7) << 4);
        char* base = (char*)sA + wid * 1024;
        *(u32*)(base + ((lane * 4 + 0  ) ^ X)) = pack2bf(a0.x, a0.y);
        *(u32*)(base + ((lane * 4 + 256) ^ X)) = pack2bf(a1.x, a1.y);
        *(u32*)(base + ((lane * 4 + 512) ^ X)) = pack2bf(a2.x, a2.y);
        *(u32*)(base + ((lane * 4 + 768) ^ X)) = pack2bf(a3.x, a3.y);
    }
    __syncthreads();

    // MFMA: [16,512] @ [512,128]; waves 0..7 -> col tile wid*16
    if (wid < 8) {
        int lr = lane & 15, lk = lane >> 4;
        u32 X = (u32)((lr & 7) << 4);
        const char* ab = (const char*)sA + lr * 1024;
        const u16* bb = Wt + lk * 1024 + (wid * 16 + lr) * 8;
        f32x4 acc = {};
        #pragma unroll
        for (int ks = 0; ks < 16; ks++) {
            bf16x8 af = *(const bf16x8*)(ab + ((ks * 64 + lk * 16) ^ X));
            bf16x8 bfv = *(const bf16x8*)(bb + ks * 4096);
            acc = __builtin_amdgcn_mfma_f32_16x16x32_bf16(af, bfv, acc, 0, 0, 0);
        }

        // epilogue: col = lane&15 (+tile), row = (lane>>4)*4 + r
        int colg = wid * 16 + lr;
        float bv = bias[colg];
        #pragma unroll
        for (int r = 0; r < 4; r++) {
            int nn = n0 + lk * 4 + r;
            if (nn < N) {
                size_t idx = (size_t)nn * DIM + colg;
                float v = acc[r] + bv;
                v = v > 0.f ? v : 0.01f * v;
                if (MODE == 1)
                    outf[idx] = 0.25f * (x0[idx] + bf2f(z1b[idx]) + bf2f(z2b[idx]) + v);
                else
                    outb[idx] = f2bf(v);
            }
        }
    }
}

// ---------------- launch ----------------

extern "C" void kernel_launch(void* const* d_in, const int* in_sizes, int n_in,
                              void* d_out, int out_size, void* d_ws, size_t ws_size,
                              hipStream_t stream) {
    const float* x     = (const float*)d_in[0];
    const int*   eidx  = (const int*)d_in[1];
    const int*   etype = (const int*)d_in[2];
    const float* eattr = (const float*)d_in[3];
    const float* W1 = (const float*)d_in[4];
    const float* b1 = (const float*)d_in[5];
    const float* W2 = (const float*)d_in[6];
    const float* b2 = (const float*)d_in[7];
    const float* W3 = (const float*)d_in[8];
    const float* b3 = (const float*)d_in[9];

    const int E = in_sizes[2];
    const int N = in_sizes[0] / DIM;
    const int* row = eidx;
    const int* col = eidx + E;

    char* w = (char*)d_ws;
    size_t off = 0;
    auto alloc = [&](size_t bytes) { size_t o = off; off = (off + bytes + 255) & ~255ULL; return o; };
    size_t deg_off = alloc((size_t)N * 4);
    int*   deg  = (int*)(w + deg_off);
    int*   fill = (int*)(w + alloc((size_t)N * 4));
    size_t zero_bytes = off - deg_off;
    u64*   ep   = (u64*)(w + alloc((size_t)N * SLOTS * 8));
    u16*   xb   = (u16*)(w + alloc((size_t)N * DIM * 2));
    u16*   z1b  = (u16*)(w + alloc((size_t)N * DIM * 2));
    u16*   z2b  = (u16*)(w + alloc((size_t)N * DIM * 2));
    u16*   Wt1  = (u16*)(w + alloc(65536 * 2));
    u16*   Wt2  = (u16*)(w + alloc(65536 * 2));
    u16*   Wt3  = (u16*)(w + alloc(65536 * 2));

    hipMemsetAsync(deg, 0, zero_bytes, stream);

    int nx4 = N * DIM / 4;
    int nEb = (E + 1023) / 1024;    // 4 edges per thread
    int nXb = (nx4 + 255) / 256;

    k_setup<<<nEb + nXb + 768, 256, 0, stream>>>(row, col, etype, eattr, E, deg, fill, ep,
                                                 x, xb, nx4, W1, W2, W3, Wt1, Wt2, Wt3, nEb, nXb);
    k_norm<<<(N + 3) / 4, 256, 0, stream>>>(fill, deg, ep, N);

    int grid = (N + 15) / 16;
    k_layer<0><<<grid, 1024, 0, stream>>>(xb,  fill, ep, Wt1, b1, nullptr, nullptr, nullptr, nullptr, z1b, N);
    k_layer<0><<<grid, 1024, 0, stream>>>(z1b, fill, ep, Wt2, b2, nullptr, nullptr, nullptr, nullptr, z2b, N);
    k_layer<1><<<grid, 1024, 0, stream>>>(z2b, fill, ep, Wt3, b3, x, z1b, z2b, (float*)d_out, nullptr, N);
}

// Round 10
// 242.175 us; speedup vs baseline: 7.4046x; 1.0093x over previous
//
#include <hip/hip_runtime.h>

#define DIM 128
#define SLOTS 64

typedef __attribute__((ext_vector_type(8))) short bf16x8;
typedef __attribute__((ext_vector_type(4))) float f32x4;
typedef unsigned short u16;
typedef unsigned int u32;
typedef unsigned long long u64;

__device__ __forceinline__ float bf2f(u32 u) {
    return __builtin_bit_cast(float, u << 16);
}
__device__ __forceinline__ u16 f2bf(float f) {
    u32 u = __builtin_bit_cast(u32, f);
    u = (u + 0x7FFFu + ((u >> 16) & 1u)) >> 16;   // RNE
    return (u16)u;
}
__device__ __forceinline__ u32 pack2bf(float a, float b) {
    return (u32)f2bf(a) | ((u32)f2bf(b) << 16);
}

// ---------------- fused setup: deg/fill atomics (4 edges/thread) + bucket scatter + x->bf16 + Wt x3 ----------------
// bucket lo32 = (c << 8) | et  -> byte offset into xb is (lo & 0xFFFFFF00), type is (lo & 3)

__global__ __launch_bounds__(256) void k_setup(const int* __restrict__ row, const int* __restrict__ col,
                                               const int* __restrict__ et, const float* __restrict__ ew,
                                               int E, int* __restrict__ deg, int* __restrict__ fill,
                                               u64* __restrict__ ep,
                                               const float* __restrict__ x, u16* __restrict__ xb, int nx4,
                                               const float* __restrict__ W1, const float* __restrict__ W2,
                                               const float* __restrict__ W3,
                                               u16* __restrict__ Wt1, u16* __restrict__ Wt2,
                                               u16* __restrict__ Wt3, int nEb, int nXb) {
    int b = blockIdx.x, tid = threadIdx.x;
    if (b < nEb) {
        int e0 = (b * 256 + tid) * 4;
        #pragma unroll
        for (int i = 0; i < 4; i++) {
            int e = e0 + i;
            if (e < E) {
                int r = row[e], c = col[e];
                atomicAdd(&deg[c], 1);                    // in-degree (col counts)
                int pos = atomicAdd(&fill[r], 1);         // bucket slot for row
                if (pos < SLOTS)
                    ep[(size_t)r * SLOTS + pos] =
                        ((u64)__builtin_bit_cast(u32, ew[e]) << 32) | (u32)((c << 8) | et[e]);
            }
        }
    } else if (b < nEb + nXb) {
        int i = (b - nEb) * 256 + tid;
        if (i < nx4) {
            float4 v = ((const float4*)x)[i];
            ushort4 o;
            o.x = f2bf(v.x); o.y = f2bf(v.y); o.z = f2bf(v.z); o.w = f2bf(v.w);
            ((ushort4*)xb)[i] = o;
        }
    } else {
        int b2 = b - nEb - nXb;                    // 0..767
        const float* W = b2 < 256 ? W1 : (b2 < 512 ? W2 : W3);
        u16* Wt = b2 < 256 ? Wt1 : (b2 < 512 ? Wt2 : Wt3);
        int o = (b2 & 255) * 256 + tid;            // 0..65535
        // natural fragment order: o = chunk*1024 + col*8 + s, k = chunk*8 + s = t*128 + i
        int chunk = o >> 10;
        int c = (o >> 3) & 127;
        int k = chunk * 8 + (o & 7);
        Wt[o] = f2bf(W[(k >> 7) * 16384 + (k & 127) * 128 + c]);
    }
}

// ---------------- k_norm: fold full norm (rsqrt inline) into bucket weights + zero-pad to x8 ----------------

__global__ __launch_bounds__(256) void k_norm(const int* __restrict__ fill,
                                              const int* __restrict__ deg,
                                              u64* __restrict__ ep, int N) {
    int wid = threadIdx.x >> 6, lane = threadIdx.x & 63;
    int n = blockIdx.x * 4 + wid;
    if (n >= N) return;
    int cnt = fill[n]; if (cnt > SLOTS) cnt = SLOTS;
    int padded = (cnt + 7) & ~7;
    int dgn = deg[n];
    float dn = dgn > 0 ? rsqrtf((float)dgn) : 0.f;
    u64* eb = ep + (size_t)n * SLOTS;
    if (lane < cnt) {
        u64 q = eb[lane];
        u32 lo = (u32)q;
        int dgc = deg[lo >> 8];
        float dc = dgc > 0 ? rsqrtf((float)dgc) : 0.f;
        float wgt = __builtin_bit_cast(float, (u32)(q >> 32)) * dn * dc;
        eb[lane] = ((u64)__builtin_bit_cast(u32, wgt) << 32) | lo;
    } else if (lane < padded) {
        eb[lane] = 0;   // zero weight, col 0, type 0
    }
}

// ---------------- fused layer: bucket gather-aggregate -> LDS -> MFMA -> epilogue ----------------
// block = 1024 thr / 16 waves = 16 nodes, one node per wave. BRANCHLESS accumulate:
// one straight-line block per round of 8 -> all 8 gathers issued before the waitcnt.

template <int MODE>
__global__ __launch_bounds__(1024, 2) void k_layer(const u16* __restrict__ src,
                                                   const int* __restrict__ fill,
                                                   const u64* __restrict__ ep,
                                                   const u16* __restrict__ Wt,
                                                   const float* __restrict__ bias,
                                                   const float* __restrict__ x0,
                                                   const u16* __restrict__ z1b,
                                                   const u16* __restrict__ z2b,
                                                   float* __restrict__ outf,
                                                   u16* __restrict__ outb, int N) {
    __shared__ u16 sA[16 * 512];   // 16 KB
    int tid = threadIdx.x, wid = tid >> 6, lane = tid & 63;
    int n0 = blockIdx.x * 16;
    int n = n0 + wid;

    float2 a0 = {0.f, 0.f}, a1 = {0.f, 0.f}, a2 = {0.f, 0.f}, a3 = {0.f, 0.f};
    int cnt = 0;
    if (n < N) {
        cnt = fill[n];
        if (cnt > SLOTS) cnt = SLOTS;
    }
    const u64* eb = ep + (size_t)n * SLOTS;
    const char* xbase = (const char*)src + lane * 4;

#define ACC(lo, wu, v) { \
        float w_  = __builtin_bit_cast(float, (wu)); \
        float vl_ = __builtin_bit_cast(float, (v) << 16); \
        float vh_ = __builtin_bit_cast(float, (v) & 0xFFFF0000u); \
        u32 t_ = (lo) & 3u; \
        float w0_ = t_ == 0u ? w_ : 0.f; \
        float w1_ = t_ == 1u ? w_ : 0.f; \
        float w2_ = t_ == 2u ? w_ : 0.f; \
        float w3_ = t_ == 3u ? w_ : 0.f; \
        a0.x += vl_ * w0_; a0.y += vh_ * w0_; \
        a1.x += vl_ * w1_; a1.y += vh_ * w1_; \
        a2.x += vl_ * w2_; a2.y += vh_ * w2_; \
        a3.x += vl_ * w3_; a3.y += vh_ * w3_; }

    // buckets zero-padded to multiple of 8 -> unmasked rounds; 64B bucket chunk as 4x uint4
    for (int j = 0; j < cnt; j += 8) {
        const uint4* ebv = (const uint4*)(eb + j);
        uint4 qa = ebv[0], qb = ebv[1], qc = ebv[2], qd = ebv[3];
        u32 o0 = qa.x & 0xFFFFFF00u, o1 = qa.z & 0xFFFFFF00u;
        u32 o2 = qb.x & 0xFFFFFF00u, o3 = qb.z & 0xFFFFFF00u;
        u32 o4 = qc.x & 0xFFFFFF00u, o5 = qc.z & 0xFFFFFF00u;
        u32 o6 = qd.x & 0xFFFFFF00u, o7 = qd.z & 0xFFFFFF00u;
        u32 v0 = *(const u32*)(xbase + o0);
        u32 v1 = *(const u32*)(xbase + o1);
        u32 v2 = *(const u32*)(xbase + o2);
        u32 v3 = *(const u32*)(xbase + o3);
        u32 v4 = *(const u32*)(xbase + o4);
        u32 v5 = *(const u32*)(xbase + o5);
        u32 v6 = *(const u32*)(xbase + o6);
        u32 v7 = *(const u32*)(xbase + o7);
        ACC(qa.x, qa.y, v0); ACC(qa.z, qa.w, v1);
        ACC(qb.x, qb.y, v2); ACC(qb.z, qb.w, v3);
        ACC(qc.x, qc.y, v4); ACC(qc.z, qc.w, v5);
        ACC(qd.x, qd.y, v6); ACC(qd.z, qd.w, v7);
    }
#undef ACC

    // LDS store: row = wid (node), k = t*128 + 2*lane; swizzle byte ^= (row&7)<<4
    {
        u32 X = (u32)((wid & 7) << 4);
        char* base = (char*)sA + wid * 1024;
        *(u32*)(base + ((lane * 4 + 0  ) ^ X)) = pack2bf(a0.x, a0.y);
        *(u32*)(base + ((lane * 4 + 256) ^ X)) = pack2bf(a1.x, a1.y);
        *(u32*)(base + ((lane * 4 + 512) ^ X)) = pack2bf(a2.x, a2.y);
        *(u32*)(base + ((lane * 4 + 768) ^ X)) = pack2bf(a3.x, a3.y);
    }
    __syncthreads();

    // MFMA: [16,512] @ [512,128]; waves 0..7 -> col tile wid*16
    if (wid < 8) {
        int lr = lane & 15, lk = lane >> 4;
        u32 X = (u32)((lr & 7) << 4);
        const char* ab = (const char*)sA + lr * 1024;
        const u16* bb = Wt + lk * 1024 + (wid * 16 + lr) * 8;
        f32x4 acc = {};
        #pragma unroll
        for (int ks = 0; ks < 16; ks++) {
            bf16x8 af = *(const bf16x8*)(ab + ((ks * 64 + lk * 16) ^ X));
            bf16x8 bfv = *(const bf16x8*)(bb + ks * 4096);
            acc = __builtin_amdgcn_mfma_f32_16x16x32_bf16(af, bfv, acc, 0, 0, 0);
        }

        // epilogue: col = lane&15 (+tile), row = (lane>>4)*4 + r
        int colg = wid * 16 + lr;
        float bv = bias[colg];
        #pragma unroll
        for (int r = 0; r < 4; r++) {
            int nn = n0 + lk * 4 + r;
            if (nn < N) {
                size_t idx = (size_t)nn * DIM + colg;
                float v = acc[r] + bv;
                v = v > 0.f ? v : 0.01f * v;
                if (MODE == 1)
                    outf[idx] = 0.25f * (x0[idx] + bf2f(z1b[idx]) + bf2f(z2b[idx]) + v);
                else
                    outb[idx] = f2bf(v);
            }
        }
    }
}

// ---------------- launch ----------------

extern "C" void kernel_launch(void* const* d_in, const int* in_sizes, int n_in,
                              void* d_out, int out_size, void* d_ws, size_t ws_size,
                              hipStream_t stream) {
    const float* x     = (const float*)d_in[0];
    const int*   eidx  = (const int*)d_in[1];
    const int*   etype = (const int*)d_in[2];
    const float* eattr = (const float*)d_in[3];
    const float* W1 = (const float*)d_in[4];
    const float* b1 = (const float*)d_in[5];
    const float* W2 = (const float*)d_in[6];
    const float* b2 = (const float*)d_in[7];
    const float* W3 = (const float*)d_in[8];
    const float* b3 = (const float*)d_in[9];

    const int E = in_sizes[2];
    const int N = in_sizes[0] / DIM;
    const int* row = eidx;
    const int* col = eidx + E;

    char* w = (char*)d_ws;
    size_t off = 0;
    auto alloc = [&](size_t bytes) { size_t o = off; off = (off + bytes + 255) & ~255ULL; return o; };
    size_t deg_off = alloc((size_t)N * 4);
    int*   deg  = (int*)(w + deg_off);
    int*   fill = (int*)(w + alloc((size_t)N * 4));
    size_t zero_bytes = off - deg_off;
    u64*   ep   = (u64*)(w + alloc((size_t)N * SLOTS * 8));
    u16*   xb   = (u16*)(w + alloc((size_t)N * DIM * 2));
    u16*   z1b  = (u16*)(w + alloc((size_t)N * DIM * 2));
    u16*   z2b  = (u16*)(w + alloc((size_t)N * DIM * 2));
    u16*   Wt1  = (u16*)(w + alloc(65536 * 2));
    u16*   Wt2  = (u16*)(w + alloc(65536 * 2));
    u16*   Wt3  = (u16*)(w + alloc(65536 * 2));

    hipMemsetAsync(deg, 0, zero_bytes, stream);

    int nx4 = N * DIM / 4;
    int nEb = (E + 1023) / 1024;    // 4 edges per thread
    int nXb = (nx4 + 255) / 256;

    k_setup<<<nEb + nXb + 768, 256, 0, stream>>>(row, col, etype, eattr, E, deg, fill, ep,
                                                 x, xb, nx4, W1, W2, W3, Wt1, Wt2, Wt3, nEb, nXb);
    k_norm<<<(N + 3) / 4, 256, 0, stream>>>(fill, deg, ep, N);

    int grid = (N + 15) / 16;
    k_layer<0><<<grid, 1024, 0, stream>>>(xb,  fill, ep, Wt1, b1, nullptr, nullptr, nullptr, nullptr, z1b, N);
    k_layer<0><<<grid, 1024, 0, stream>>>(z1b, fill, ep, Wt2, b2, nullptr, nullptr, nullptr, nullptr, z2b, N);
    k_layer<1><<<grid, 1024, 0, stream>>>(z2b, fill, ep, Wt3, b3, x, z1b, z2b, (float*)d_out, nullptr, N);
}

// Round 11
// 235.838 us; speedup vs baseline: 7.6036x; 1.0269x over previous
//
#include <hip/hip_runtime.h>

#define DIM 128
#define SLOTS 64

typedef __attribute__((ext_vector_type(8))) short bf16x8;
typedef __attribute__((ext_vector_type(4))) float f32x4;
typedef unsigned short u16;
typedef unsigned int u32;
typedef unsigned long long u64;

__device__ __forceinline__ float bf2f(u32 u) {
    return __builtin_bit_cast(float, u << 16);
}
__device__ __forceinline__ u16 f2bf(float f) {
    u32 u = __builtin_bit_cast(u32, f);
    u = (u + 0x7FFFu + ((u >> 16) & 1u)) >> 16;   // RNE
    return (u16)u;
}
__device__ __forceinline__ u32 pack2bf(float a, float b) {
    return (u32)f2bf(a) | ((u32)f2bf(b) << 16);
}

// ---------------- fused setup: deg/fill atomics (4 edges/thread) + bucket scatter + x->bf16 + Wt x3 ----------------
// bucket lo32 = (c << 8) | et  -> byte offset into xb is (lo & 0xFFFFFF00), type is (lo & 3)

__global__ __launch_bounds__(256) void k_setup(const int* __restrict__ row, const int* __restrict__ col,
                                               const int* __restrict__ et, const float* __restrict__ ew,
                                               int E, int* __restrict__ deg, int* __restrict__ fill,
                                               u64* __restrict__ ep,
                                               const float* __restrict__ x, u16* __restrict__ xb, int nx4,
                                               const float* __restrict__ W1, const float* __restrict__ W2,
                                               const float* __restrict__ W3,
                                               u16* __restrict__ Wt1, u16* __restrict__ Wt2,
                                               u16* __restrict__ Wt3, int nEb, int nXb) {
    int b = blockIdx.x, tid = threadIdx.x;
    if (b < nEb) {
        int e0 = (b * 256 + tid) * 4;
        #pragma unroll
        for (int i = 0; i < 4; i++) {
            int e = e0 + i;
            if (e < E) {
                int r = row[e], c = col[e];
                atomicAdd(&deg[c], 1);                    // in-degree (col counts)
                int pos = atomicAdd(&fill[r], 1);         // bucket slot for row
                if (pos < SLOTS)
                    ep[(size_t)r * SLOTS + pos] =
                        ((u64)__builtin_bit_cast(u32, ew[e]) << 32) | (u32)((c << 8) | et[e]);
            }
        }
    } else if (b < nEb + nXb) {
        int i = (b - nEb) * 256 + tid;
        if (i < nx4) {
            float4 v = ((const float4*)x)[i];
            ushort4 o;
            o.x = f2bf(v.x); o.y = f2bf(v.y); o.z = f2bf(v.z); o.w = f2bf(v.w);
            ((ushort4*)xb)[i] = o;
        }
    } else {
        int b2 = b - nEb - nXb;                    // 0..767
        const float* W = b2 < 256 ? W1 : (b2 < 512 ? W2 : W3);
        u16* Wt = b2 < 256 ? Wt1 : (b2 < 512 ? Wt2 : Wt3);
        int o = (b2 & 255) * 256 + tid;            // 0..65535
        // natural fragment order: o = chunk*1024 + col*8 + s, k = chunk*8 + s = t*128 + i
        int chunk = o >> 10;
        int c = (o >> 3) & 127;
        int k = chunk * 8 + (o & 7);
        Wt[o] = f2bf(W[(k >> 7) * 16384 + (k & 127) * 128 + c]);
    }
}

// ---------------- k_norm: fold full norm (rsqrt inline) into bucket weights + zero-pad to x8 ----------------

__global__ __launch_bounds__(256) void k_norm(const int* __restrict__ fill,
                                              const int* __restrict__ deg,
                                              u64* __restrict__ ep, int N) {
    int wid = threadIdx.x >> 6, lane = threadIdx.x & 63;
    int n = blockIdx.x * 4 + wid;
    if (n >= N) return;
    int cnt = fill[n]; if (cnt > SLOTS) cnt = SLOTS;
    int padded = (cnt + 7) & ~7;
    int dgn = deg[n];
    float dn = dgn > 0 ? rsqrtf((float)dgn) : 0.f;
    u64* eb = ep + (size_t)n * SLOTS;
    if (lane < cnt) {
        u64 q = eb[lane];
        u32 lo = (u32)q;
        int dgc = deg[lo >> 8];
        float dc = dgc > 0 ? rsqrtf((float)dgc) : 0.f;
        float wgt = __builtin_bit_cast(float, (u32)(q >> 32)) * dn * dc;
        eb[lane] = ((u64)__builtin_bit_cast(u32, wgt) << 32) | lo;
    } else if (lane < padded) {
        eb[lane] = 0;   // zero weight, col 0, type 0
    }
}

// ---------------- fused layer: SCALARIZED bucket gather-aggregate -> LDS -> MFMA -> epilogue ----------------
// block = 1024 thr / 16 waves = 16 nodes, one node per wave. Bucket entries, gather offsets,
// and type-selected weights are wave-uniform -> readfirstlane pushes decode+selects to SALU;
// gathers become SGPR-base loads (1 dest VGPR each); VALU/edge = 2 unpack + 8 fmac (SGPR mult).

template <int MODE>
__global__ __launch_bounds__(1024, 2) void k_layer(const u16* __restrict__ src,
                                                   const int* __restrict__ fill,
                                                   const u64* __restrict__ ep,
                                                   const u16* __restrict__ Wt,
                                                   const float* __restrict__ bias,
                                                   const float* __restrict__ x0,
                                                   const u16* __restrict__ z1b,
                                                   const u16* __restrict__ z2b,
                                                   float* __restrict__ outf,
                                                   u16* __restrict__ outb, int N) {
    __shared__ u16 sA[16 * 512];   // 16 KB
    int tid = threadIdx.x, wid = tid >> 6, lane = tid & 63;
    int n0 = blockIdx.x * 16;
    int n = n0 + wid;

    float2 a0 = {0.f, 0.f}, a1 = {0.f, 0.f}, a2 = {0.f, 0.f}, a3 = {0.f, 0.f};
    int cnt = 0;
    if (n < N) {
        cnt = fill[n];
        if (cnt > SLOTS) cnt = SLOTS;
    }
    const u64* eb = ep + (size_t)n * SLOTS;
    const char* xbase = (const char*)src + lane * 4;

#define RFL(x) __builtin_amdgcn_readfirstlane((int)(x))

#define EDGE(lo_, wu_, v_) { \
        float w_  = __builtin_bit_cast(float, (u32)(wu_)); \
        float vl_ = __builtin_bit_cast(float, (v_) << 16); \
        float vh_ = __builtin_bit_cast(float, (v_) & 0xFFFF0000u); \
        u32 t_ = (u32)(lo_) & 3u; \
        float w0_ = t_ == 0u ? w_ : 0.f; \
        float w1_ = t_ == 1u ? w_ : 0.f; \
        float w2_ = t_ == 2u ? w_ : 0.f; \
        float w3_ = t_ == 3u ? w_ : 0.f; \
        a0.x = fmaf(vl_, w0_, a0.x); a0.y = fmaf(vh_, w0_, a0.y); \
        a1.x = fmaf(vl_, w1_, a1.x); a1.y = fmaf(vh_, w1_, a1.y); \
        a2.x = fmaf(vl_, w2_, a2.x); a2.y = fmaf(vh_, w2_, a2.y); \
        a3.x = fmaf(vl_, w3_, a3.x); a3.y = fmaf(vh_, w3_, a3.y); }

    // buckets zero-padded to multiple of 8 -> unmasked rounds; all bucket data scalarized
    for (int j = 0; j < cnt; j += 8) {
        const uint4* ebv = (const uint4*)(eb + j);
        uint4 qa = ebv[0], qb = ebv[1], qc = ebv[2], qd = ebv[3];
        u32 lo0 = (u32)RFL(qa.x), wu0 = (u32)RFL(qa.y);
        u32 lo1 = (u32)RFL(qa.z), wu1 = (u32)RFL(qa.w);
        u32 lo2 = (u32)RFL(qb.x), wu2 = (u32)RFL(qb.y);
        u32 lo3 = (u32)RFL(qb.z), wu3 = (u32)RFL(qb.w);
        u32 lo4 = (u32)RFL(qc.x), wu4 = (u32)RFL(qc.y);
        u32 lo5 = (u32)RFL(qc.z), wu5 = (u32)RFL(qc.w);
        u32 lo6 = (u32)RFL(qd.x), wu6 = (u32)RFL(qd.y);
        u32 lo7 = (u32)RFL(qd.z), wu7 = (u32)RFL(qd.w);
        u32 v0 = *(const u32*)(xbase + (lo0 & 0xFFFFFF00u));
        u32 v1 = *(const u32*)(xbase + (lo1 & 0xFFFFFF00u));
        u32 v2 = *(const u32*)(xbase + (lo2 & 0xFFFFFF00u));
        u32 v3 = *(const u32*)(xbase + (lo3 & 0xFFFFFF00u));
        u32 v4 = *(const u32*)(xbase + (lo4 & 0xFFFFFF00u));
        u32 v5 = *(const u32*)(xbase + (lo5 & 0xFFFFFF00u));
        u32 v6 = *(const u32*)(xbase + (lo6 & 0xFFFFFF00u));
        u32 v7 = *(const u32*)(xbase + (lo7 & 0xFFFFFF00u));
        EDGE(lo0, wu0, v0); EDGE(lo1, wu1, v1);
        EDGE(lo2, wu2, v2); EDGE(lo3, wu3, v3);
        EDGE(lo4, wu4, v4); EDGE(lo5, wu5, v5);
        EDGE(lo6, wu6, v6); EDGE(lo7, wu7, v7);
    }
#undef EDGE
#undef RFL

    // LDS store: row = wid (node), k = t*128 + 2*lane; swizzle byte ^= (row&7)<<4
    {
        u32 X = (u32)((wid & 7) << 4);
        char* base = (char*)sA + wid * 1024;
        *(u32*)(base + ((lane * 4 + 0  ) ^ X)) = pack2bf(a0.x, a0.y);
        *(u32*)(base + ((lane * 4 + 256) ^ X)) = pack2bf(a1.x, a1.y);
        *(u32*)(base + ((lane * 4 + 512) ^ X)) = pack2bf(a2.x, a2.y);
        *(u32*)(base + ((lane * 4 + 768) ^ X)) = pack2bf(a3.x, a3.y);
    }
    __syncthreads();

    // MFMA: [16,512] @ [512,128]; waves 0..7 -> col tile wid*16
    if (wid < 8) {
        int lr = lane & 15, lk = lane >> 4;
        u32 X = (u32)((lr & 7) << 4);
        const char* ab = (const char*)sA + lr * 1024;
        const u16* bb = Wt + lk * 1024 + (wid * 16 + lr) * 8;
        f32x4 acc = {};
        #pragma unroll
        for (int ks = 0; ks < 16; ks++) {
            bf16x8 af = *(const bf16x8*)(ab + ((ks * 64 + lk * 16) ^ X));
            bf16x8 bfv = *(const bf16x8*)(bb + ks * 4096);
            acc = __builtin_amdgcn_mfma_f32_16x16x32_bf16(af, bfv, acc, 0, 0, 0);
        }

        // epilogue: col = lane&15 (+tile), row = (lane>>4)*4 + r
        int colg = wid * 16 + lr;
        float bv = bias[colg];
        #pragma unroll
        for (int r = 0; r < 4; r++) {
            int nn = n0 + lk * 4 + r;
            if (nn < N) {
                size_t idx = (size_t)nn * DIM + colg;
                float v = acc[r] + bv;
                v = v > 0.f ? v : 0.01f * v;
                if (MODE == 1)
                    outf[idx] = 0.25f * (x0[idx] + bf2f(z1b[idx]) + bf2f(z2b[idx]) + v);
                else
                    outb[idx] = f2bf(v);
            }
        }
    }
}

// ---------------- launch ----------------

extern "C" void kernel_launch(void* const* d_in, const int* in_sizes, int n_in,
                              void* d_out, int out_size, void* d_ws, size_t ws_size,
                              hipStream_t stream) {
    const float* x     = (const float*)d_in[0];
    const int*   eidx  = (const int*)d_in[1];
    const int*   etype = (const int*)d_in[2];
    const float* eattr = (const float*)d_in[3];
    const float* W1 = (const float*)d_in[4];
    const float* b1 = (const float*)d_in[5];
    const float* W2 = (const float*)d_in[6];
    const float* b2 = (const float*)d_in[7];
    const float* W3 = (const float*)d_in[8];
    const float* b3 = (const float*)d_in[9];

    const int E = in_sizes[2];
    const int N = in_sizes[0] / DIM;
    const int* row = eidx;
    const int* col = eidx + E;

    char* w = (char*)d_ws;
    size_t off = 0;
    auto alloc = [&](size_t bytes) { size_t o = off; off = (off + bytes + 255) & ~255ULL; return o; };
    size_t deg_off = alloc((size_t)N * 4);
    int*   deg  = (int*)(w + deg_off);
    int*   fill = (int*)(w + alloc((size_t)N * 4));
    size_t zero_bytes = off - deg_off;
    u64*   ep   = (u64*)(w + alloc((size_t)N * SLOTS * 8));
    u16*   xb   = (u16*)(w + alloc((size_t)N * DIM * 2));
    u16*   z1b  = (u16*)(w + alloc((size_t)N * DIM * 2));
    u16*   z2b  = (u16*)(w + alloc((size_t)N * DIM * 2));
    u16*   Wt1  = (u16*)(w + alloc(65536 * 2));
    u16*   Wt2  = (u16*)(w + alloc(65536 * 2));
    u16*   Wt3  = (u16*)(w + alloc(65536 * 2));

    hipMemsetAsync(deg, 0, zero_bytes, stream);

    int nx4 = N * DIM / 4;
    int nEb = (E + 1023) / 1024;    // 4 edges per thread
    int nXb = (nx4 + 255) / 256;

    k_setup<<<nEb + nXb + 768, 256, 0, stream>>>(row, col, etype, eattr, E, deg, fill, ep,
                                                 x, xb, nx4, W1, W2, W3, Wt1, Wt2, Wt3, nEb, nXb);
    k_norm<<<(N + 3) / 4, 256, 0, stream>>>(fill, deg, ep, N);

    int grid = (N + 15) / 16;
    k_layer<0><<<grid, 1024, 0, stream>>>(xb,  fill, ep, Wt1, b1, nullptr, nullptr, nullptr, nullptr, z1b, N);
    k_layer<0><<<grid, 1024, 0, stream>>>(z1b, fill, ep, Wt2, b2, nullptr, nullptr, nullptr, nullptr, z2b, N);
    k_layer<1><<<grid, 1024, 0, stream>>>(z2b, fill, ep, Wt3, b3, x, z1b, z2b, (float*)d_out, nullptr, N);
}